// Round 1
// 170.087 us; speedup vs baseline: 1.0473x; 1.0473x over previous
//
#include <hip/hip_runtime.h>
#include <hip/hip_bf16.h>
#include <stdint.h>

// ---------------------------------------------------------------------------
// pcnn round 11: attack per-wave latency (occupancy is structurally capped).
//  - Split-accumulator MFMA chains: even/odd taps -> dep depth 9->5, 4
//    independent chains per pixel (a0e/a0o/a1e/a1o), merged with v_add before
//    relu+pack. Same for logits (ae/ao).
//  - Batched staging: 2 chunks of 25 in-flight global loads, then the LDS
//    convert+stores -- pays cold-HBM latency ~2x instead of ~50x.
//  - Everything else identical to R10 (register-resident hidden state,
//    permuted weight rows, 18 hoisted A-frags/layer, zero barriers).
// ---------------------------------------------------------------------------

typedef short bf16x8 __attribute__((ext_vector_type(8)));
typedef float f32x4  __attribute__((ext_vector_type(4)));

// d_ws: WALL bf16 [8 layers][9 taps][32 o(permuted rows)][32 c] @0 (73728 u16)
//   l=0: conv0 (c<8), l=1..6: mid, l=7: logits (natural rows, o<6)
// f32 @ byte 147456: BALL[8][32](permuted) @0, WPOST[18][3][25] @256, BPOST[18] @1606
#define WSB_N     73728
#define WSF_BYTE  147456
#define WSF_BALL  0
#define WSF_WPOST 256
#define WSF_BPOST 1606
#define WSF_N     1624

__device__ __forceinline__ float b2f(unsigned short u) {
  union { unsigned int u; float f; } v; v.u = ((unsigned int)u) << 16; return v.f;
}
__device__ __forceinline__ unsigned short f2b(float f) {
  union { float f; unsigned int u; } v; v.f = f;
  unsigned int r = v.u + 0x7fffu + ((v.u >> 16) & 1u);  // RNE
  return (unsigned short)(r >> 16);
}
__device__ __forceinline__ unsigned int pk2(float lo, float hi) {
  __hip_bfloat162 h = __float22bfloat162_rn(make_float2(lo, hi));
  union { __hip_bfloat162 h; unsigned int u; } v; v.h = h; return v.u;
}
__device__ __forceinline__ bool sniff_is_f32(const void* w0raw) {
  const unsigned short* q = (const unsigned short*)w0raw;
  int hits = 0;
  #pragma unroll
  for (int i = 0; i < 64; ++i) {
    unsigned int e = (q[i] >> 7) & 0xFFu;
    if (e >= 130u) ++hits;
  }
  return hits > 0;
}
__device__ __forceinline__ float ldw(const void* p, long idx, bool f32) {
  return f32 ? ((const float*)p)[idx] : b2f(((const unsigned short*)p)[idx]);
}
// C-row m -> B-k-slot permutation
__device__ __forceinline__ int kperm(int m) {
  return (m < 16) ? ((m >> 2) * 8 + (m & 3))
                  : (((m - 16) >> 2) * 8 + 4 + (m & 3));
}

// ---------------- weight pre-pack (identical to R9/R10, verified) ----------
__global__ void prep_weights(const void* __restrict__ w0,
                             const void* __restrict__ b0,
                             const void* __restrict__ wm,
                             const void* __restrict__ bm,
                             const void* __restrict__ wl,
                             const void* __restrict__ bl,
                             const void* __restrict__ wp,
                             const void* __restrict__ bp,
                             unsigned short* __restrict__ wsb,
                             float* __restrict__ wsf) {
  const bool f32 = sniff_is_f32(w0);
  int e = blockIdx.x * blockDim.x + threadIdx.x;
  if (e < WSB_N) {                        // WALL[l][t][o32][c32]
    int l = e / 9216, r = e % 9216, t = r / 1024, r2 = r % 1024;
    int o = r2 >> 5, c = r2 & 31;
    float v = 0.f;
    if (l < 7) {
      int co = kperm(o);                  // original out-channel at row o
      if (co < 25) {
        if (l == 0) { if (c < 8)  v = ldw(w0, (co * 8 + c) * 9 + t, f32); }
        else        { if (c < 25) v = ldw(wm, (((l - 1) * 25 + co) * 25 + c) * 9 + t, f32); }
      }
    } else {
      if (o < 6 && c < 25) v = ldw(wl, (o * 25 + c) * 9 + t, f32);
    }
    wsb[e] = f2b(v);
  } else {
    int q = e - WSB_N;
    if (q < 256) {                        // BALL[l][32] (rows permuted, l<7)
      int l = q >> 5, m = q & 31;
      float v = 0.f;
      if (l < 7) {
        int co = kperm(m);
        if (co < 25) v = (l == 0) ? ldw(b0, co, f32) : ldw(bm, (l - 1) * 25 + co, f32);
      } else {
        if (m < 6) v = ldw(bl, m, f32);
      }
      wsf[WSF_BALL + q] = v;
    } else if (q < 256 + 1350) {
      wsf[WSF_WPOST + (q - 256)] = ldw(wp, q - 256, f32);
    } else if (q < WSF_N) {
      wsf[WSF_BPOST + (q - 1606)] = ldw(bp, q - 1606, f32);
    }
  }
}

// ---------------- main kernel: one wave per 16 patches ---------------------
__global__ __launch_bounds__(64)
__attribute__((amdgpu_waves_per_eu(2, 2)))
void pcnn_mfma(
    const void* __restrict__ inp,
    const void* __restrict__ w0raw,
    const unsigned short* __restrict__ wsb,
    const float* __restrict__ wsf,
    void* __restrict__ out) {
  __shared__ __align__(16) unsigned char u9600[9600];  // stage(6400B) then smb(9600B)
  __shared__ float in3[1200];                          // [b16][3c][25px] f32
  __shared__ float colb[288];                          // [b16][18oc]
  short* stage = (short*)u9600;                        // [25px][16b][8c]
  float* smb   = (float*)u9600;                        // [25px][16b][6]

  const bool f32m = sniff_is_f32(w0raw);
  const int lane = threadIdx.x;         // 0..63
  const int col  = lane & 15;           // MFMA n (patch) / m-row group
  const int quad = lane >> 4;
  const long g   = blockIdx.x;          // group of 16 patches

  // ---- stage input [b][8c][25px] -> stage[px][b][c8] + in3 (f32) ----
  // Batched: issue 25 independent loads, then convert+store. Cold-HBM
  // latency (~900cy) is paid ~2x, not ~50x.
  #pragma unroll 1
  for (int c0 = 0; c0 < 3200; c0 += 1600) {
    float v[25];
    #pragma unroll
    for (int j = 0; j < 25; ++j)
      v[j] = ldw(inp, g * 3200 + c0 + j * 64 + lane, f32m);
    #pragma unroll
    for (int j = 0; j < 25; ++j) {
      const int e = c0 + j * 64 + lane;
      int b = e / 200, r = e % 200, c = r / 25, px = r % 25;
      stage[px * 128 + b * 8 + c] = f2b(v[j]);
      if (c < 3) in3[b * 75 + c * 25 + px] = v[j];
    }
  }
  __asm__ volatile("s_waitcnt lgkmcnt(0)" ::: "memory");

  // ---- layer-0 B-frags: quad0 holds ch0..7, other quads zero ----
  bf16x8 X[25], Y[25];
  #pragma unroll
  for (int p = 0; p < 25; ++p) {
    union { bf16x8 v; uint4 q4; } t;
    t.q4 = make_uint4(0u, 0u, 0u, 0u);
    if (quad == 0) t.q4 = *(const uint4*)(stage + p * 128 + col * 8);
    X[p] = t.v;
  }

  // ---- conv layer: A-frags hoisted, px loop fully unrolled ----
  // Split accumulators (even/odd taps): dep depth 9->5, 4 independent MFMA
  // chains per pixel instead of 2; merged with v_add before relu+pack.
  auto conv = [&](const bf16x8 (&in)[25], bf16x8 (&outp)[25], int l) {
    const unsigned short* WA = wsb + l * 9216;
    bf16x8 A0[9], A1[9];
    #pragma unroll
    for (int t = 0; t < 9; ++t) {
      A0[t] = *(const bf16x8*)(WA + t * 1024 + col * 32 + quad * 8);
      A1[t] = *(const bf16x8*)(WA + t * 1024 + (16 + col) * 32 + quad * 8);
    }
    const f32x4 bias0 = *(const f32x4*)(wsf + WSF_BALL + l * 32 + quad * 4);
    const f32x4 bias1 = *(const f32x4*)(wsf + WSF_BALL + l * 32 + 16 + quad * 4);
    #pragma unroll
    for (int p = 0; p < 25; ++p) {
      const int py = p / 5, pxx = p % 5;
      f32x4 a0e = bias0, a1e = bias1;
      f32x4 a0o = {0.f, 0.f, 0.f, 0.f}, a1o = {0.f, 0.f, 0.f, 0.f};
      #pragma unroll
      for (int dy = -1; dy <= 1; ++dy)
        #pragma unroll
        for (int dx = -1; dx <= 1; ++dx)
          if ((unsigned)(py + dy) < 5u && (unsigned)(pxx + dx) < 5u) {
            const int t = (dy + 1) * 3 + (dx + 1);
            const int q = p + dy * 5 + dx;
            if (t & 1) {
              a0o = __builtin_amdgcn_mfma_f32_16x16x32_bf16(A0[t], in[q], a0o, 0, 0, 0);
              a1o = __builtin_amdgcn_mfma_f32_16x16x32_bf16(A1[t], in[q], a1o, 0, 0, 0);
            } else {
              a0e = __builtin_amdgcn_mfma_f32_16x16x32_bf16(A0[t], in[q], a0e, 0, 0, 0);
              a1e = __builtin_amdgcn_mfma_f32_16x16x32_bf16(A1[t], in[q], a1e, 0, 0, 0);
            }
          }
      // merge chains + relu + pack: with permuted weight rows this IS the
      // next B-frag
      union { bf16x8 v; unsigned int uu[4]; } nb;
      nb.uu[0] = pk2(fmaxf(a0e[0] + a0o[0], 0.f), fmaxf(a0e[1] + a0o[1], 0.f));
      nb.uu[1] = pk2(fmaxf(a0e[2] + a0o[2], 0.f), fmaxf(a0e[3] + a0o[3], 0.f));
      nb.uu[2] = pk2(fmaxf(a1e[0] + a1o[0], 0.f), fmaxf(a1e[1] + a1o[1], 0.f));
      nb.uu[3] = pk2(fmaxf(a1e[2] + a1o[2], 0.f), fmaxf(a1e[3] + a1o[3], 0.f));
      outp[p] = nb.v;
    }
  };

  // layers: 0: X->Y; then pairs {Y->X, X->Y} so only ONE array crosses the
  // back edge (100 VGPRs), letting in/out liveness interleave inside.
  conv(X, Y, 0);
  #pragma unroll 1
  for (int i = 0; i < 3; ++i) {
    conv(Y, X, 2 * i + 1);
    conv(X, Y, 2 * i + 2);
  }
  // final hidden in Y

  // ---- logits (natural rows, o<6) + in-register softmax -> smb ----
  {
    const unsigned short* WA = wsb + 7 * 9216;
    bf16x8 A[9];
    #pragma unroll
    for (int t = 0; t < 9; ++t)
      A[t] = *(const bf16x8*)(WA + t * 1024 + col * 32 + quad * 8);
    const f32x4 biasl = *(const f32x4*)(wsf + WSF_BALL + 7 * 32 + quad * 4);
    #pragma unroll
    for (int p = 0; p < 25; ++p) {
      const int py = p / 5, pxx = p % 5;
      f32x4 ae = biasl, ao = {0.f, 0.f, 0.f, 0.f};
      #pragma unroll
      for (int dy = -1; dy <= 1; ++dy)
        #pragma unroll
        for (int dx = -1; dx <= 1; ++dx)
          if ((unsigned)(py + dy) < 5u && (unsigned)(pxx + dx) < 5u) {
            const int t = (dy + 1) * 3 + (dx + 1);
            const int q = p + dy * 5 + dx;
            if (t & 1)
              ao = __builtin_amdgcn_mfma_f32_16x16x32_bf16(A[t], Y[q], ao, 0, 0, 0);
            else
              ae = __builtin_amdgcn_mfma_f32_16x16x32_bf16(A[t], Y[q], ae, 0, 0, 0);
          }
      f32x4 a;
      a[0] = ae[0] + ao[0]; a[1] = ae[1] + ao[1];
      a[2] = ae[2] + ao[2]; a[3] = ae[3] + ao[3];
      // quad0: rows0-3 = ch0-3; quad1 regs0,1 = ch4,5 (pull via xor 16)
      float l4 = __shfl_xor(a[0], 16);
      float l5 = __shfl_xor(a[1], 16);
      if (quad == 0) {
        float m = fmaxf(fmaxf(fmaxf(a[0], a[1]), fmaxf(a[2], a[3])), fmaxf(l4, l5));
        float e0 = __expf(a[0] - m), e1 = __expf(a[1] - m), e2 = __expf(a[2] - m);
        float e3 = __expf(a[3] - m), e4 = __expf(l4 - m), e5 = __expf(l5 - m);
        float inv = 1.f / (e0 + e1 + e2 + e3 + e4 + e5);
        float* sp = smb + p * 96 + col * 6;
        sp[0] = e0 * inv; sp[1] = e1 * inv; sp[2] = e2 * inv;
        sp[3] = e3 * inv; sp[4] = e4 * inv; sp[5] = e5 * inv;
      }
    }
  }
  __asm__ volatile("s_waitcnt lgkmcnt(0)" ::: "memory");

  // ---- colors: 5x5 VALID conv on first 3 input channels (from in3) ----
  for (int j = lane; j < 288; j += 64) {
    int b = j / 18, oc = j % 18;
    float s = wsf[WSF_BPOST + oc];
    #pragma unroll
    for (int ic = 0; ic < 3; ++ic)
      #pragma unroll
      for (int px = 0; px < 25; ++px)
        s = fmaf(wsf[WSF_WPOST + (oc * 3 + ic) * 25 + px], in3[b * 75 + ic * 25 + px], s);
    colb[b * 18 + oc] = s;
  }
  __asm__ volatile("s_waitcnt lgkmcnt(0)" ::: "memory");

  // ---- mix + store: out[b][c][p] = sum_w colors[b][c*6+w] * sm[p][b][w] ----
  for (int e = lane; e < 1200; e += 64) {
    int b = e / 75, r = e % 75, c = r / 25, p = r % 25;
    float v = 0.f;
    #pragma unroll
    for (int w = 0; w < 6; ++w)
      v = fmaf(colb[b * 18 + c * 6 + w], smb[p * 96 + b * 6 + w], v);
    const long oidx = g * 1200 + e;
    if (f32m) ((float*)out)[oidx] = v;
    else      ((unsigned short*)out)[oidx] = f2b(v);
  }
}

extern "C" void kernel_launch(void* const* d_in, const int* in_sizes, int n_in,
                              void* d_out, int out_size, void* d_ws, size_t ws_size,
                              hipStream_t stream) {
  unsigned short* wsb = (unsigned short*)d_ws;
  float* wsf = (float*)((char*)d_ws + WSF_BYTE);
  const int B = in_sizes[0] / 200;  // 32768

  const int prep_n = WSB_N + WSF_N;  // 75352
  prep_weights<<<(prep_n + 255) / 256, 256, 0, stream>>>(
      d_in[1], d_in[2], d_in[3], d_in[4], d_in[5], d_in[6], d_in[7], d_in[8],
      wsb, wsf);
  pcnn_mfma<<<B / 16, 64, 0, stream>>>(d_in[0], d_in[1], wsb, wsf, d_out);
}

// Round 2
// 159.384 us; speedup vs baseline: 1.1176x; 1.0671x over previous
//
#include <hip/hip_runtime.h>
#include <hip/hip_bf16.h>
#include <stdint.h>

// ---------------------------------------------------------------------------
// pcnn round 12: kill the scalar colors loop + wave arbitration.
//  - colors (18x75 @ 75x16) computed as MFMA GEMM: 3 K-chunks x 2 M-halves,
//    double-bf16 (hi + lo residual) for f32-level accuracy -> 18 MFMAs
//    replacing ~375 lane-divergent global loads + 375 LDS reads + 375 FMAs.
//    Packed wpost frags live in layer-7 rows o>=6 (read by logits A-frags but
//    those output rows are discarded; MFMA rows are independent) -> zero
//    workspace growth. A-frags loaded at kernel top, in flight during staging.
//  - s_setprio(1) around each pixel's MFMA tap cluster (T5): waves are
//    independent, drift into role diversity -> scheduler favors MFMA wave.
//  - LDS re-packed: stage(6400) + inpk(6144) + colb(1152) = 13696 B,
//    smb aliases phase-1 region. 8 blocks/CU preserved.
// ---------------------------------------------------------------------------

typedef short bf16x8 __attribute__((ext_vector_type(8)));
typedef float f32x4  __attribute__((ext_vector_type(4)));

// d_ws: WALL bf16 [8 layers][9 taps][32 o(permuted rows)][32 c] @0 (73728 u16)
//   l=0: conv0 (c<8), l=1..6: mid, l=7 rows<6: logits; l=7 rows>=6: wpost frags
// f32 @ byte 147456: BALL[8][32](permuted) @0, BP32[32] @256 (zero-padded bpost)
#define WSB_N     73728
#define WSB_EMB   6144
#define WSF_BYTE  147456
#define WSF_BALL  0
#define WSF_BP32  256
#define WSF_N     1624

__device__ __forceinline__ float b2f(unsigned short u) {
  union { unsigned int u; float f; } v; v.u = ((unsigned int)u) << 16; return v.f;
}
__device__ __forceinline__ unsigned short f2b(float f) {
  union { float f; unsigned int u; } v; v.f = f;
  unsigned int r = v.u + 0x7fffu + ((v.u >> 16) & 1u);  // RNE
  return (unsigned short)(r >> 16);
}
__device__ __forceinline__ unsigned int pk2(float lo, float hi) {
  __hip_bfloat162 h = __float22bfloat162_rn(make_float2(lo, hi));
  union { __hip_bfloat162 h; unsigned int u; } v; v.h = h; return v.u;
}
__device__ __forceinline__ bool sniff_is_f32(const void* w0raw) {
  const unsigned short* q = (const unsigned short*)w0raw;
  int hits = 0;
  #pragma unroll
  for (int i = 0; i < 64; ++i) {
    unsigned int e = (q[i] >> 7) & 0xFFu;
    if (e >= 130u) ++hits;
  }
  return hits > 0;
}
__device__ __forceinline__ float ldw(const void* p, long idx, bool f32) {
  return f32 ? ((const float*)p)[idx] : b2f(((const unsigned short*)p)[idx]);
}
// C-row m -> B-k-slot permutation
__device__ __forceinline__ int kperm(int m) {
  return (m < 16) ? ((m >> 2) * 8 + (m & 3))
                  : (((m - 16) >> 2) * 8 + 4 + (m & 3));
}

// ---------------- weight pre-pack ------------------------------------------
__global__ void prep_weights(const void* __restrict__ w0,
                             const void* __restrict__ b0,
                             const void* __restrict__ wm,
                             const void* __restrict__ bm,
                             const void* __restrict__ wl,
                             const void* __restrict__ bl,
                             const void* __restrict__ wp,
                             const void* __restrict__ bp,
                             unsigned short* __restrict__ wsb,
                             float* __restrict__ wsf) {
  const bool f32 = sniff_is_f32(w0);
  int e = blockIdx.x * blockDim.x + threadIdx.x;
  if (e < WSB_N) {                        // WALL[l][t][o32][c32]
    int l = e / 9216, r = e % 9216, t = r / 1024, r2 = r % 1024;
    int o = r2 >> 5, c = r2 & 31;
    if (l == 7 && o >= 6) return;         // reserved for wpost frags
    float v = 0.f;
    if (l < 7) {
      int co = kperm(o);                  // original out-channel at row o
      if (co < 25) {
        if (l == 0) { if (c < 8)  v = ldw(w0, (co * 8 + c) * 9 + t, f32); }
        else        { if (c < 25) v = ldw(wm, (((l - 1) * 25 + co) * 25 + c) * 9 + t, f32); }
      }
    } else {
      if (c < 25) v = ldw(wl, (o * 25 + c) * 9 + t, f32);
    }
    wsb[e] = f2b(v);
  } else if (e < WSB_N + WSB_EMB) {
    // wpost frag pack: conceptual [hl2][chunk3][o32][k32], physical at
    // layer-7 rows >= 6: rowidx = hl*96+chunk*32+o -> (tap, row 6+rowidx%26)
    int idx = e - WSB_N;
    int hl = idx / 3072, rem = idx % 3072;
    int chunk = rem / 1024, r2 = rem % 1024;
    int o = r2 >> 5, k = r2 & 31;
    float w = (o < 18 && k < 25) ? ldw(wp, (o * 3 + chunk) * 25 + k, f32) : 0.f;
    unsigned short hi = f2b(w);
    unsigned short val = hl ? f2b(w - b2f(hi)) : hi;
    int rowidx = hl * 96 + chunk * 32 + o;
    int t = rowidx / 26, rr = 6 + rowidx % 26;
    wsb[7 * 9216 + t * 1024 + rr * 32 + k] = val;
  } else {
    int q = e - WSB_N - WSB_EMB;
    if (q < 256) {                        // BALL[l][32] (rows permuted, l<7)
      int l = q >> 5, m = q & 31;
      float v = 0.f;
      if (l < 7) {
        int co = kperm(m);
        if (co < 25) v = (l == 0) ? ldw(b0, co, f32) : ldw(bm, (l - 1) * 25 + co, f32);
      } else {
        if (m < 6) v = ldw(bl, m, f32);
      }
      wsf[WSF_BALL + q] = v;
    } else if (q < 288) {                 // BP32: zero-padded bpost
      int oc = q - 256;
      wsf[WSF_BP32 + oc] = (oc < 18) ? ldw(bp, oc, f32) : 0.f;
    }
  }
}

// ---------------- main kernel: one wave per 16 patches ---------------------
__global__ __launch_bounds__(64)
__attribute__((amdgpu_waves_per_eu(2, 2)))
void pcnn_mfma(
    const void* __restrict__ inp,
    const void* __restrict__ w0raw,
    const unsigned short* __restrict__ wsb,
    const float* __restrict__ wsf,
    void* __restrict__ out) {
  __shared__ __align__(16) unsigned char pool[13696];
  short* stage = (short*)pool;              // [25px][16b][8c]      phase 1
  short* inpk  = (short*)(pool + 6400);     // [hl2][ic3][b16][k32] phase 1
  float* colb  = (float*)(pool + 12544);    // [b16][18oc]          both
  float* smb   = (float*)pool;              // [25px][16b][6]       phase 2

  const bool f32m = sniff_is_f32(w0raw);
  const int lane = threadIdx.x;         // 0..63
  const int col  = lane & 15;           // MFMA n (patch) / m-row group
  const int quad = lane >> 4;
  const long g   = blockIdx.x;          // group of 16 patches

  // ---- colors A-frags + bias: issue now, consumed after staging ----
  bf16x8 WC[2][3][2];
  #pragma unroll
  for (int hl = 0; hl < 2; ++hl)
    #pragma unroll
    for (int ch = 0; ch < 3; ++ch)
      #pragma unroll
      for (int hf = 0; hf < 2; ++hf) {
        const int rowidx = hl * 96 + ch * 32 + hf * 16 + col;
        const int t = rowidx / 26, rr = 6 + rowidx % 26;
        WC[hl][ch][hf] = *(const bf16x8*)(wsb + 7 * 9216 + t * 1024 + rr * 32 + quad * 8);
      }
  f32x4 c0 = *(const f32x4*)(wsf + WSF_BP32 + quad * 4);
  f32x4 c1 = *(const f32x4*)(wsf + WSF_BP32 + 16 + quad * 4);

  // ---- zero inpk pad slots k=25..31 (garbage NaN x 0-weight = NaN!) ----
  for (int i = lane; i < 672; i += 64) {
    int s = 25 + i % 7, rest = i / 7;     // rest = (hl*3+ic)*16+b
    inpk[rest * 32 + s] = 0;
  }

  // ---- stage input [b][8c][25px] -> stage[px][b][c8] + inpk hi/lo ----
  #pragma unroll 1
  for (int c0i = 0; c0i < 3200; c0i += 1600) {
    float v[25];
    #pragma unroll
    for (int j = 0; j < 25; ++j)
      v[j] = ldw(inp, g * 3200 + c0i + j * 64 + lane, f32m);
    #pragma unroll
    for (int j = 0; j < 25; ++j) {
      const int e = c0i + j * 64 + lane;
      int b = e / 200, r = e % 200, c = r / 25, px = r % 25;
      unsigned short hi = f2b(v[j]);
      stage[px * 128 + b * 8 + c] = hi;
      if (c < 3) {
        inpk[((0 * 3 + c) * 16 + b) * 32 + px] = hi;
        inpk[((1 * 3 + c) * 16 + b) * 32 + px] = f2b(v[j] - b2f(hi));
      }
    }
  }
  __asm__ volatile("s_waitcnt lgkmcnt(0)" ::: "memory");

  // ---- colors GEMM: 18 MFMAs, double-bf16 ----
  #pragma unroll
  for (int ch = 0; ch < 3; ++ch) {
    bf16x8 Bhi = *(const bf16x8*)(inpk + ((0 * 3 + ch) * 16 + col) * 32 + quad * 8);
    bf16x8 Blo = *(const bf16x8*)(inpk + ((1 * 3 + ch) * 16 + col) * 32 + quad * 8);
    c0 = __builtin_amdgcn_mfma_f32_16x16x32_bf16(WC[0][ch][0], Bhi, c0, 0, 0, 0);
    c0 = __builtin_amdgcn_mfma_f32_16x16x32_bf16(WC[0][ch][0], Blo, c0, 0, 0, 0);
    c0 = __builtin_amdgcn_mfma_f32_16x16x32_bf16(WC[1][ch][0], Bhi, c0, 0, 0, 0);
    c1 = __builtin_amdgcn_mfma_f32_16x16x32_bf16(WC[0][ch][1], Bhi, c1, 0, 0, 0);
    c1 = __builtin_amdgcn_mfma_f32_16x16x32_bf16(WC[0][ch][1], Blo, c1, 0, 0, 0);
    c1 = __builtin_amdgcn_mfma_f32_16x16x32_bf16(WC[1][ch][1], Bhi, c1, 0, 0, 0);
  }
  // lane (patch=col): c0 regs r -> oc quad*4+r; c1 regs -> oc 16+quad*4+r
  #pragma unroll
  for (int r = 0; r < 4; ++r) colb[col * 18 + quad * 4 + r] = c0[r];
  if (quad == 0) { colb[col * 18 + 16] = c1[0]; colb[col * 18 + 17] = c1[1]; }

  // ---- layer-0 B-frags: quad0 holds ch0..7, other quads zero ----
  bf16x8 X[25], Y[25];
  #pragma unroll
  for (int p = 0; p < 25; ++p) {
    union { bf16x8 v; uint4 q4; } t;
    t.q4 = make_uint4(0u, 0u, 0u, 0u);
    if (quad == 0) t.q4 = *(const uint4*)(stage + p * 128 + col * 8);
    X[p] = t.v;
  }

  // ---- conv layer: A-frags hoisted, px loop fully unrolled ----
  auto conv = [&](const bf16x8 (&in)[25], bf16x8 (&outp)[25], int l) {
    const unsigned short* WA = wsb + l * 9216;
    bf16x8 A0[9], A1[9];
    #pragma unroll
    for (int t = 0; t < 9; ++t) {
      A0[t] = *(const bf16x8*)(WA + t * 1024 + col * 32 + quad * 8);
      A1[t] = *(const bf16x8*)(WA + t * 1024 + (16 + col) * 32 + quad * 8);
    }
    const f32x4 bias0 = *(const f32x4*)(wsf + WSF_BALL + l * 32 + quad * 4);
    const f32x4 bias1 = *(const f32x4*)(wsf + WSF_BALL + l * 32 + 16 + quad * 4);
    #pragma unroll
    for (int p = 0; p < 25; ++p) {
      const int py = p / 5, pxx = p % 5;
      f32x4 a0e = bias0, a1e = bias1;
      f32x4 a0o = {0.f, 0.f, 0.f, 0.f}, a1o = {0.f, 0.f, 0.f, 0.f};
      __builtin_amdgcn_s_setprio(1);
      #pragma unroll
      for (int dy = -1; dy <= 1; ++dy)
        #pragma unroll
        for (int dx = -1; dx <= 1; ++dx)
          if ((unsigned)(py + dy) < 5u && (unsigned)(pxx + dx) < 5u) {
            const int t = (dy + 1) * 3 + (dx + 1);
            const int q = p + dy * 5 + dx;
            if (t & 1) {
              a0o = __builtin_amdgcn_mfma_f32_16x16x32_bf16(A0[t], in[q], a0o, 0, 0, 0);
              a1o = __builtin_amdgcn_mfma_f32_16x16x32_bf16(A1[t], in[q], a1o, 0, 0, 0);
            } else {
              a0e = __builtin_amdgcn_mfma_f32_16x16x32_bf16(A0[t], in[q], a0e, 0, 0, 0);
              a1e = __builtin_amdgcn_mfma_f32_16x16x32_bf16(A1[t], in[q], a1e, 0, 0, 0);
            }
          }
      __builtin_amdgcn_s_setprio(0);
      // merge chains + relu + pack -> next layer's B-frag (rows permuted)
      union { bf16x8 v; unsigned int uu[4]; } nb;
      nb.uu[0] = pk2(fmaxf(a0e[0] + a0o[0], 0.f), fmaxf(a0e[1] + a0o[1], 0.f));
      nb.uu[1] = pk2(fmaxf(a0e[2] + a0o[2], 0.f), fmaxf(a0e[3] + a0o[3], 0.f));
      nb.uu[2] = pk2(fmaxf(a1e[0] + a1o[0], 0.f), fmaxf(a1e[1] + a1o[1], 0.f));
      nb.uu[3] = pk2(fmaxf(a1e[2] + a1o[2], 0.f), fmaxf(a1e[3] + a1o[3], 0.f));
      outp[p] = nb.v;
    }
  };

  conv(X, Y, 0);
  #pragma unroll 1
  for (int i = 0; i < 3; ++i) {
    conv(Y, X, 2 * i + 1);
    conv(X, Y, 2 * i + 2);
  }
  // final hidden in Y

  // ---- logits (rows<6 natural) + in-register softmax -> smb ----
  {
    const unsigned short* WA = wsb + 7 * 9216;
    bf16x8 A[9];
    #pragma unroll
    for (int t = 0; t < 9; ++t)
      A[t] = *(const bf16x8*)(WA + t * 1024 + col * 32 + quad * 8);
    const f32x4 biasl = *(const f32x4*)(wsf + WSF_BALL + 7 * 32 + quad * 4);
    #pragma unroll
    for (int p = 0; p < 25; ++p) {
      const int py = p / 5, pxx = p % 5;
      f32x4 ae = biasl, ao = {0.f, 0.f, 0.f, 0.f};
      __builtin_amdgcn_s_setprio(1);
      #pragma unroll
      for (int dy = -1; dy <= 1; ++dy)
        #pragma unroll
        for (int dx = -1; dx <= 1; ++dx)
          if ((unsigned)(py + dy) < 5u && (unsigned)(pxx + dx) < 5u) {
            const int t = (dy + 1) * 3 + (dx + 1);
            const int q = p + dy * 5 + dx;
            if (t & 1)
              ao = __builtin_amdgcn_mfma_f32_16x16x32_bf16(A[t], Y[q], ao, 0, 0, 0);
            else
              ae = __builtin_amdgcn_mfma_f32_16x16x32_bf16(A[t], Y[q], ae, 0, 0, 0);
          }
      __builtin_amdgcn_s_setprio(0);
      f32x4 a;
      a[0] = ae[0] + ao[0]; a[1] = ae[1] + ao[1];
      a[2] = ae[2] + ao[2]; a[3] = ae[3] + ao[3];
      // quad0: rows0-3 = ch0-3; quad1 regs0,1 = ch4,5 (pull via xor 16)
      float l4 = __shfl_xor(a[0], 16);
      float l5 = __shfl_xor(a[1], 16);
      if (quad == 0) {
        float m = fmaxf(fmaxf(fmaxf(a[0], a[1]), fmaxf(a[2], a[3])), fmaxf(l4, l5));
        float e0 = __expf(a[0] - m), e1 = __expf(a[1] - m), e2 = __expf(a[2] - m);
        float e3 = __expf(a[3] - m), e4 = __expf(l4 - m), e5 = __expf(l5 - m);
        float inv = 1.f / (e0 + e1 + e2 + e3 + e4 + e5);
        float* sp = smb + p * 96 + col * 6;
        sp[0] = e0 * inv; sp[1] = e1 * inv; sp[2] = e2 * inv;
        sp[3] = e3 * inv; sp[4] = e4 * inv; sp[5] = e5 * inv;
      }
    }
  }
  __asm__ volatile("s_waitcnt lgkmcnt(0)" ::: "memory");

  // ---- mix + store: out[b][c][p] = sum_w colors[b][c*6+w] * sm[p][b][w] ----
  for (int e = lane; e < 1200; e += 64) {
    int b = e / 75, r = e % 75, c = r / 25, p = r % 25;
    float v = 0.f;
    #pragma unroll
    for (int w = 0; w < 6; ++w)
      v = fmaf(colb[b * 18 + c * 6 + w], smb[p * 96 + b * 6 + w], v);
    const long oidx = g * 1200 + e;
    if (f32m) ((float*)out)[oidx] = v;
    else      ((unsigned short*)out)[oidx] = f2b(v);
  }
}

extern "C" void kernel_launch(void* const* d_in, const int* in_sizes, int n_in,
                              void* d_out, int out_size, void* d_ws, size_t ws_size,
                              hipStream_t stream) {
  unsigned short* wsb = (unsigned short*)d_ws;
  float* wsf = (float*)((char*)d_ws + WSF_BYTE);
  const int B = in_sizes[0] / 200;  // 32768

  const int prep_n = WSB_N + WSB_EMB + 288;  // 80160
  prep_weights<<<(prep_n + 255) / 256, 256, 0, stream>>>(
      d_in[1], d_in[2], d_in[3], d_in[4], d_in[5], d_in[6], d_in[7], d_in[8],
      wsb, wsf);
  pcnn_mfma<<<B / 16, 64, 0, stream>>>(d_in[0], d_in[1], wsb, wsf, d_out);
}

// Round 3
// 155.001 us; speedup vs baseline: 1.1492x; 1.0283x over previous
//
#include <hip/hip_runtime.h>
#include <hip/hip_bf16.h>
#include <stdint.h>

// ---------------------------------------------------------------------------
// pcnn round 13: software-pipelined pack + LDS de-conflict.
//  - Deferred pack: pixel p's MFMA cluster issues, THEN pixel p-1's
//    relu+pack (producer finished >=349cy ago) -> the MFMA-latency +
//    20-VALU tail no longer sits between clusters. Same for the logits
//    softmax tail (shfl+exp+stores deferred one pixel).
//  - LDS conflict fix (measured 1.0e7 conflict-cycles): stage stride
//    128->136 shorts (272B, 16B-aligned rows, banks spread 4/px), smb
//    stride 96->98 floats. Staging writes and mix reads were ~25-way.
//  - Everything else identical to R12 (colors GEMM in layer-7 spare rows,
//    setprio around clusters, register-resident hidden state).
// ---------------------------------------------------------------------------

typedef short bf16x8 __attribute__((ext_vector_type(8)));
typedef float f32x4  __attribute__((ext_vector_type(4)));

// d_ws: WALL bf16 [8 layers][9 taps][32 o(permuted rows)][32 c] @0 (73728 u16)
//   l=0: conv0 (c<8), l=1..6: mid, l=7 rows<6: logits; l=7 rows>=6: wpost frags
// f32 @ byte 147456: BALL[8][32](permuted) @0, BP32[32] @256 (zero-padded bpost)
#define WSB_N     73728
#define WSB_EMB   6144
#define WSF_BYTE  147456
#define WSF_BALL  0
#define WSF_BP32  256

// LDS layout (bytes):
//   phase1: stage @0 (25*136*2=6800), inpk @6800 (6144), colb @12944 (1152)
//   phase2: smb @0 (25*98*4=9800; stage+inpk dead), colb persists
#define L_STAGE_STRIDE 136
#define L_INPK   6800
#define L_COLB   12944
#define L_POOL   14096
#define SMB_STRIDE 98

__device__ __forceinline__ float b2f(unsigned short u) {
  union { unsigned int u; float f; } v; v.u = ((unsigned int)u) << 16; return v.f;
}
__device__ __forceinline__ unsigned short f2b(float f) {
  union { float f; unsigned int u; } v; v.f = f;
  unsigned int r = v.u + 0x7fffu + ((v.u >> 16) & 1u);  // RNE
  return (unsigned short)(r >> 16);
}
__device__ __forceinline__ unsigned int pk2(float lo, float hi) {
  __hip_bfloat162 h = __float22bfloat162_rn(make_float2(lo, hi));
  union { __hip_bfloat162 h; unsigned int u; } v; v.h = h; return v.u;
}
__device__ __forceinline__ bool sniff_is_f32(const void* w0raw) {
  const unsigned short* q = (const unsigned short*)w0raw;
  int hits = 0;
  #pragma unroll
  for (int i = 0; i < 64; ++i) {
    unsigned int e = (q[i] >> 7) & 0xFFu;
    if (e >= 130u) ++hits;
  }
  return hits > 0;
}
__device__ __forceinline__ float ldw(const void* p, long idx, bool f32) {
  return f32 ? ((const float*)p)[idx] : b2f(((const unsigned short*)p)[idx]);
}
// C-row m -> B-k-slot permutation
__device__ __forceinline__ int kperm(int m) {
  return (m < 16) ? ((m >> 2) * 8 + (m & 3))
                  : (((m - 16) >> 2) * 8 + 4 + (m & 3));
}

// ---------------- weight pre-pack (identical to R12, verified) -------------
__global__ void prep_weights(const void* __restrict__ w0,
                             const void* __restrict__ b0,
                             const void* __restrict__ wm,
                             const void* __restrict__ bm,
                             const void* __restrict__ wl,
                             const void* __restrict__ bl,
                             const void* __restrict__ wp,
                             const void* __restrict__ bp,
                             unsigned short* __restrict__ wsb,
                             float* __restrict__ wsf) {
  const bool f32 = sniff_is_f32(w0);
  int e = blockIdx.x * blockDim.x + threadIdx.x;
  if (e < WSB_N) {                        // WALL[l][t][o32][c32]
    int l = e / 9216, r = e % 9216, t = r / 1024, r2 = r % 1024;
    int o = r2 >> 5, c = r2 & 31;
    if (l == 7 && o >= 6) return;         // reserved for wpost frags
    float v = 0.f;
    if (l < 7) {
      int co = kperm(o);                  // original out-channel at row o
      if (co < 25) {
        if (l == 0) { if (c < 8)  v = ldw(w0, (co * 8 + c) * 9 + t, f32); }
        else        { if (c < 25) v = ldw(wm, (((l - 1) * 25 + co) * 25 + c) * 9 + t, f32); }
      }
    } else {
      if (c < 25) v = ldw(wl, (o * 25 + c) * 9 + t, f32);
    }
    wsb[e] = f2b(v);
  } else if (e < WSB_N + WSB_EMB) {
    // wpost frag pack: conceptual [hl2][chunk3][o32][k32], physical at
    // layer-7 rows >= 6: rowidx = hl*96+chunk*32+o -> (tap, row 6+rowidx%26)
    int idx = e - WSB_N;
    int hl = idx / 3072, rem = idx % 3072;
    int chunk = rem / 1024, r2 = rem % 1024;
    int o = r2 >> 5, k = r2 & 31;
    float w = (o < 18 && k < 25) ? ldw(wp, (o * 3 + chunk) * 25 + k, f32) : 0.f;
    unsigned short hi = f2b(w);
    unsigned short val = hl ? f2b(w - b2f(hi)) : hi;
    int rowidx = hl * 96 + chunk * 32 + o;
    int t = rowidx / 26, rr = 6 + rowidx % 26;
    wsb[7 * 9216 + t * 1024 + rr * 32 + k] = val;
  } else {
    int q = e - WSB_N - WSB_EMB;
    if (q < 256) {                        // BALL[l][32] (rows permuted, l<7)
      int l = q >> 5, m = q & 31;
      float v = 0.f;
      if (l < 7) {
        int co = kperm(m);
        if (co < 25) v = (l == 0) ? ldw(b0, co, f32) : ldw(bm, (l - 1) * 25 + co, f32);
      } else {
        if (m < 6) v = ldw(bl, m, f32);
      }
      wsf[WSF_BALL + q] = v;
    } else if (q < 288) {                 // BP32: zero-padded bpost
      int oc = q - 256;
      wsf[WSF_BP32 + oc] = (oc < 18) ? ldw(bp, oc, f32) : 0.f;
    }
  }
}

// ---------------- main kernel: one wave per 16 patches ---------------------
__global__ __launch_bounds__(64)
__attribute__((amdgpu_waves_per_eu(2, 2)))
void pcnn_mfma(
    const void* __restrict__ inp,
    const void* __restrict__ w0raw,
    const unsigned short* __restrict__ wsb,
    const float* __restrict__ wsf,
    void* __restrict__ out) {
  __shared__ __align__(16) unsigned char pool[L_POOL];
  short* stage = (short*)pool;              // [25px][136] phase 1
  short* inpk  = (short*)(pool + L_INPK);   // [hl2][ic3][b16][k32] phase 1
  float* colb  = (float*)(pool + L_COLB);   // [b16][18oc] both phases
  float* smb   = (float*)pool;              // [25px][98] phase 2

  const bool f32m = sniff_is_f32(w0raw);
  const int lane = threadIdx.x;         // 0..63
  const int col  = lane & 15;           // MFMA n (patch) / m-row group
  const int quad = lane >> 4;
  const long g   = blockIdx.x;          // group of 16 patches

  // ---- colors A-frags + bias: issue now, consumed after staging ----
  bf16x8 WC[2][3][2];
  #pragma unroll
  for (int hl = 0; hl < 2; ++hl)
    #pragma unroll
    for (int ch = 0; ch < 3; ++ch)
      #pragma unroll
      for (int hf = 0; hf < 2; ++hf) {
        const int rowidx = hl * 96 + ch * 32 + hf * 16 + col;
        const int t = rowidx / 26, rr = 6 + rowidx % 26;
        WC[hl][ch][hf] = *(const bf16x8*)(wsb + 7 * 9216 + t * 1024 + rr * 32 + quad * 8);
      }
  f32x4 c0 = *(const f32x4*)(wsf + WSF_BP32 + quad * 4);
  f32x4 c1 = *(const f32x4*)(wsf + WSF_BP32 + 16 + quad * 4);

  // ---- zero inpk pad slots k=25..31 (garbage NaN x 0-weight = NaN!) ----
  for (int i = lane; i < 672; i += 64) {
    int s = 25 + i % 7, rest = i / 7;     // rest = (hl*3+ic)*16+b
    inpk[rest * 32 + s] = 0;
  }

  // ---- stage input [b][8c][25px] -> stage[px][b*8+c] + inpk hi/lo ----
  #pragma unroll 1
  for (int c0i = 0; c0i < 3200; c0i += 1600) {
    float v[25];
    #pragma unroll
    for (int j = 0; j < 25; ++j)
      v[j] = ldw(inp, g * 3200 + c0i + j * 64 + lane, f32m);
    #pragma unroll
    for (int j = 0; j < 25; ++j) {
      const int e = c0i + j * 64 + lane;
      int b = e / 200, r = e % 200, c = r / 25, px = r % 25;
      unsigned short hi = f2b(v[j]);
      stage[px * L_STAGE_STRIDE + b * 8 + c] = hi;
      if (c < 3) {
        inpk[((0 * 3 + c) * 16 + b) * 32 + px] = hi;
        inpk[((1 * 3 + c) * 16 + b) * 32 + px] = f2b(v[j] - b2f(hi));
      }
    }
  }
  __asm__ volatile("s_waitcnt lgkmcnt(0)" ::: "memory");

  // ---- colors GEMM: 18 MFMAs, double-bf16 ----
  #pragma unroll
  for (int ch = 0; ch < 3; ++ch) {
    bf16x8 Bhi = *(const bf16x8*)(inpk + ((0 * 3 + ch) * 16 + col) * 32 + quad * 8);
    bf16x8 Blo = *(const bf16x8*)(inpk + ((1 * 3 + ch) * 16 + col) * 32 + quad * 8);
    c0 = __builtin_amdgcn_mfma_f32_16x16x32_bf16(WC[0][ch][0], Bhi, c0, 0, 0, 0);
    c0 = __builtin_amdgcn_mfma_f32_16x16x32_bf16(WC[0][ch][0], Blo, c0, 0, 0, 0);
    c0 = __builtin_amdgcn_mfma_f32_16x16x32_bf16(WC[1][ch][0], Bhi, c0, 0, 0, 0);
    c1 = __builtin_amdgcn_mfma_f32_16x16x32_bf16(WC[0][ch][1], Bhi, c1, 0, 0, 0);
    c1 = __builtin_amdgcn_mfma_f32_16x16x32_bf16(WC[0][ch][1], Blo, c1, 0, 0, 0);
    c1 = __builtin_amdgcn_mfma_f32_16x16x32_bf16(WC[1][ch][1], Bhi, c1, 0, 0, 0);
  }
  // lane (patch=col): c0 regs r -> oc quad*4+r; c1 regs -> oc 16+quad*4+r
  #pragma unroll
  for (int r = 0; r < 4; ++r) colb[col * 18 + quad * 4 + r] = c0[r];
  if (quad == 0) { colb[col * 18 + 16] = c1[0]; colb[col * 18 + 17] = c1[1]; }

  // ---- layer-0 B-frags: quad0 holds ch0..7, other quads zero ----
  bf16x8 X[25], Y[25];
  #pragma unroll
  for (int p = 0; p < 25; ++p) {
    union { bf16x8 v; uint4 q4; } t;
    t.q4 = make_uint4(0u, 0u, 0u, 0u);
    if (quad == 0) t.q4 = *(const uint4*)(stage + p * L_STAGE_STRIDE + col * 8);
    X[p] = t.v;
  }

  // ---- conv layer: deferred pack (pixel p-1 packs while p's cluster runs) --
  auto conv = [&](const bf16x8 (&in)[25], bf16x8 (&outp)[25], int l) {
    const unsigned short* WA = wsb + l * 9216;
    bf16x8 A0[9], A1[9];
    #pragma unroll
    for (int t = 0; t < 9; ++t) {
      A0[t] = *(const bf16x8*)(WA + t * 1024 + col * 32 + quad * 8);
      A1[t] = *(const bf16x8*)(WA + t * 1024 + (16 + col) * 32 + quad * 8);
    }
    const f32x4 bias0 = *(const f32x4*)(wsf + WSF_BALL + l * 32 + quad * 4);
    const f32x4 bias1 = *(const f32x4*)(wsf + WSF_BALL + l * 32 + 16 + quad * 4);
    f32x4 p0e, p0o, p1e, p1o;             // previous pixel's accumulators
    #pragma unroll
    for (int p = 0; p < 25; ++p) {
      const int py = p / 5, pxx = p % 5;
      f32x4 a0e = bias0, a1e = bias1;
      f32x4 a0o = {0.f, 0.f, 0.f, 0.f}, a1o = {0.f, 0.f, 0.f, 0.f};
      __builtin_amdgcn_s_setprio(1);
      #pragma unroll
      for (int dy = -1; dy <= 1; ++dy)
        #pragma unroll
        for (int dx = -1; dx <= 1; ++dx)
          if ((unsigned)(py + dy) < 5u && (unsigned)(pxx + dx) < 5u) {
            const int t = (dy + 1) * 3 + (dx + 1);
            const int q = p + dy * 5 + dx;
            if (t & 1) {
              a0o = __builtin_amdgcn_mfma_f32_16x16x32_bf16(A0[t], in[q], a0o, 0, 0, 0);
              a1o = __builtin_amdgcn_mfma_f32_16x16x32_bf16(A1[t], in[q], a1o, 0, 0, 0);
            } else {
              a0e = __builtin_amdgcn_mfma_f32_16x16x32_bf16(A0[t], in[q], a0e, 0, 0, 0);
              a1e = __builtin_amdgcn_mfma_f32_16x16x32_bf16(A1[t], in[q], a1e, 0, 0, 0);
            }
          }
      __builtin_amdgcn_s_setprio(0);
      if (p > 0) {                        // pack PREVIOUS pixel (no stall)
        union { bf16x8 v; unsigned int uu[4]; } nb;
        nb.uu[0] = pk2(fmaxf(p0e[0] + p0o[0], 0.f), fmaxf(p0e[1] + p0o[1], 0.f));
        nb.uu[1] = pk2(fmaxf(p0e[2] + p0o[2], 0.f), fmaxf(p0e[3] + p0o[3], 0.f));
        nb.uu[2] = pk2(fmaxf(p1e[0] + p1o[0], 0.f), fmaxf(p1e[1] + p1o[1], 0.f));
        nb.uu[3] = pk2(fmaxf(p1e[2] + p1o[2], 0.f), fmaxf(p1e[3] + p1o[3], 0.f));
        outp[p - 1] = nb.v;
      }
      p0e = a0e; p0o = a0o; p1e = a1e; p1o = a1o;   // SSA-renamed, no movs
    }
    {
      union { bf16x8 v; unsigned int uu[4]; } nb;
      nb.uu[0] = pk2(fmaxf(p0e[0] + p0o[0], 0.f), fmaxf(p0e[1] + p0o[1], 0.f));
      nb.uu[1] = pk2(fmaxf(p0e[2] + p0o[2], 0.f), fmaxf(p0e[3] + p0o[3], 0.f));
      nb.uu[2] = pk2(fmaxf(p1e[0] + p1o[0], 0.f), fmaxf(p1e[1] + p1o[1], 0.f));
      nb.uu[3] = pk2(fmaxf(p1e[2] + p1o[2], 0.f), fmaxf(p1e[3] + p1o[3], 0.f));
      outp[24] = nb.v;
    }
  };

  conv(X, Y, 0);
  #pragma unroll 1
  for (int i = 0; i < 3; ++i) {
    conv(Y, X, 2 * i + 1);
    conv(X, Y, 2 * i + 2);
  }
  // final hidden in Y

  // ---- logits + deferred softmax tail -> smb ----
  {
    const unsigned short* WA = wsb + 7 * 9216;
    bf16x8 A[9];
    #pragma unroll
    for (int t = 0; t < 9; ++t)
      A[t] = *(const bf16x8*)(WA + t * 1024 + col * 32 + quad * 8);
    const f32x4 biasl = *(const f32x4*)(wsf + WSF_BALL + 7 * 32 + quad * 4);
    f32x4 pa;                              // previous pixel's merged logits
    auto tail = [&](const f32x4& a, int p) {
      float l4 = __shfl_xor(a[0], 16);
      float l5 = __shfl_xor(a[1], 16);
      if (quad == 0) {
        float m = fmaxf(fmaxf(fmaxf(a[0], a[1]), fmaxf(a[2], a[3])), fmaxf(l4, l5));
        float e0 = __expf(a[0] - m), e1 = __expf(a[1] - m), e2 = __expf(a[2] - m);
        float e3 = __expf(a[3] - m), e4 = __expf(l4 - m), e5 = __expf(l5 - m);
        float inv = 1.f / (e0 + e1 + e2 + e3 + e4 + e5);
        float* sp = smb + p * SMB_STRIDE + col * 6;
        sp[0] = e0 * inv; sp[1] = e1 * inv; sp[2] = e2 * inv;
        sp[3] = e3 * inv; sp[4] = e4 * inv; sp[5] = e5 * inv;
      }
    };
    #pragma unroll
    for (int p = 0; p < 25; ++p) {
      const int py = p / 5, pxx = p % 5;
      f32x4 ae = biasl, ao = {0.f, 0.f, 0.f, 0.f};
      __builtin_amdgcn_s_setprio(1);
      #pragma unroll
      for (int dy = -1; dy <= 1; ++dy)
        #pragma unroll
        for (int dx = -1; dx <= 1; ++dx)
          if ((unsigned)(py + dy) < 5u && (unsigned)(pxx + dx) < 5u) {
            const int t = (dy + 1) * 3 + (dx + 1);
            const int q = p + dy * 5 + dx;
            if (t & 1)
              ao = __builtin_amdgcn_mfma_f32_16x16x32_bf16(A[t], Y[q], ao, 0, 0, 0);
            else
              ae = __builtin_amdgcn_mfma_f32_16x16x32_bf16(A[t], Y[q], ae, 0, 0, 0);
          }
      __builtin_amdgcn_s_setprio(0);
      if (p > 0) tail(pa, p - 1);          // softmax for PREVIOUS pixel
      f32x4 a;
      a[0] = ae[0] + ao[0]; a[1] = ae[1] + ao[1];
      a[2] = ae[2] + ao[2]; a[3] = ae[3] + ao[3];
      pa = a;
    }
    tail(pa, 24);
  }
  __asm__ volatile("s_waitcnt lgkmcnt(0)" ::: "memory");

  // ---- mix + store: out[b][c][p] = sum_w colors[b][c*6+w] * sm[p][b][w] ----
  for (int e = lane; e < 1200; e += 64) {
    int b = e / 75, r = e % 75, c = r / 25, p = r % 25;
    float v = 0.f;
    #pragma unroll
    for (int w = 0; w < 6; ++w)
      v = fmaf(colb[b * 18 + c * 6 + w], smb[p * SMB_STRIDE + b * 6 + w], v);
    const long oidx = g * 1200 + e;
    if (f32m) ((float*)out)[oidx] = v;
    else      ((unsigned short*)out)[oidx] = f2b(v);
  }
}

extern "C" void kernel_launch(void* const* d_in, const int* in_sizes, int n_in,
                              void* d_out, int out_size, void* d_ws, size_t ws_size,
                              hipStream_t stream) {
  unsigned short* wsb = (unsigned short*)d_ws;
  float* wsf = (float*)((char*)d_ws + WSF_BYTE);
  const int B = in_sizes[0] / 200;  // 32768

  const int prep_n = WSB_N + WSB_EMB + 288;  // 80160
  prep_weights<<<(prep_n + 255) / 256, 256, 0, stream>>>(
      d_in[1], d_in[2], d_in[3], d_in[4], d_in[5], d_in[6], d_in[7], d_in[8],
      wsb, wsf);
  pcnn_mfma<<<B / 16, 64, 0, stream>>>(d_in[0], d_in[1], wsb, wsf, d_out);
}